// Round 9
// baseline (44.867 us; speedup 1.0000x reference)
//
#include <hip/hip_runtime.h>

// CP_Based: out[b,u] = rsqrt(prod_f (1+X^2)) * sum_r prod_f (k0[r,f,u] + X[b,f]*k1[r,f,u])
// X: [B,32] f32, kernel: [2,10,32,8] f32, out: [B,8] f32
//
// R1-R8 conclusion: every uniform-data delivery through memory is latency-
// exposed (s_load waits are lgkmcnt(0)-only because scalar loads return
// out-of-order -> no pipelining; VMEM broadcast 2.8x worse; LDS broadcast
// pipe-bound). This round's row loop touches NO memory: K resident in VGPRs
// (lane=(rank-slot,unit), pinned), X tile in VGPRs (coalesced load, reused
// for lane-parallel norms), per-row X made uniform via 32 v_readlane (VALU,
// 2cy, latency-free). pk_fma(x_sgpr, k1_v, k0_v) obeys the 1-SGPR rule ->
// 2 pk per f-pair. Row loop ~160cy pure issue; 4096 waves -> ~9-10us floor.

typedef float f32x2 __attribute__((ext_vector_type(2)));
typedef float f32x4 __attribute__((ext_vector_type(4)));

#define F 32
#define RANK 10
#define UNITS 8
#define RPW 32           // rows per wave
#define WPB 4            // waves per block

__global__ __launch_bounds__(64 * WPB, 2) void cp_based_kernel(
    const float* __restrict__ X,
    const float* __restrict__ K,   // [2,10,32,8] flat
    float* __restrict__ out,
    int B)
{
    const int lane = threadIdx.x;          // 0..63
    const int u = lane & 7;                // unit
    const int s = lane >> 3;               // rank-slot: set1 r=s; set2 r=8+s (s<2)
    const int wy = __builtin_amdgcn_readfirstlane(threadIdx.y);
    const int wid = blockIdx.x * WPB + wy;
    const long row0 = (long)wid * RPW;

    // ---- coalesced X tile: lane l holds X[row0 + (l>>1), 16*(l&1) + 0..15]
    f32x4 xb[4];
    {
        const float* xp = X + (row0 + (lane >> 1)) * F + 16 * (lane & 1);
#pragma unroll
        for (int j = 0; j < 4; ++j)
            xb[j] = *reinterpret_cast<const f32x4*>(xp + 4 * j);
    }

    // ---- one-time K gather into VGPRs (adjacent-lane-coalesced dword gathers)
    f32x2 k0a[16], k1a[16], k0b[16], k1b[16];
    {
        const int r1 = s;
#pragma unroll
        for (int fp = 0; fp < 16; ++fp) {
            const int f0 = 2 * fp;
            k0a[fp] = f32x2{K[((0 * RANK + r1) * F + f0) * UNITS + u],
                            K[((0 * RANK + r1) * F + f0 + 1) * UNITS + u]};
            k1a[fp] = f32x2{K[((1 * RANK + r1) * F + f0) * UNITS + u],
                            K[((1 * RANK + r1) * F + f0 + 1) * UNITS + u]};
        }
    }
    if (s < 2) {
        const int r2 = 8 + s;
#pragma unroll
        for (int fp = 0; fp < 16; ++fp) {
            const int f0 = 2 * fp;
            k0b[fp] = f32x2{K[((0 * RANK + r2) * F + f0) * UNITS + u],
                            K[((0 * RANK + r2) * F + f0 + 1) * UNITS + u]};
            k1b[fp] = f32x2{K[((1 * RANK + r2) * F + f0) * UNITS + u],
                            K[((1 * RANK + r2) * F + f0 + 1) * UNITS + u]};
        }
    } else {
#pragma unroll
        for (int fp = 0; fp < 16; ++fp) {
            k0b[fp] = f32x2{0.f, 0.f};
            k1b[fp] = f32x2{0.f, 0.f};
        }
    }
    // pin K in registers (R7 showed the compiler otherwise re-streams it)
#pragma unroll
    for (int fp = 0; fp < 16; ++fp) {
        asm("" : "+v"(k0a[fp]), "+v"(k1a[fp]));
        asm("" : "+v"(k0b[fp]), "+v"(k1b[fp]));
    }

    // ---- lane-parallel row norms: lane 2i (and 2i+1) hold rsq(nrm[row i])
    float rsqv;
    {
        const f32x4 one4 = {1.f, 1.f, 1.f, 1.f};
        f32x4 na = xb[0] * xb[0] + one4;
        f32x4 nb = xb[1] * xb[1] + one4;
        f32x4 nc = xb[2] * xb[2] + one4;
        f32x4 nd = xb[3] * xb[3] + one4;
        f32x4 nv = (na * nb) * (nc * nd);
        float npl = (nv[0] * nv[1]) * (nv[2] * nv[3]);
        npl *= __shfl_xor(npl, 1);
        rsqv = __builtin_amdgcn_rsqf(npl);
    }

    for (int i = 0; i < RPW; ++i) {
        const int lbase = 2 * i;

        // X row i -> uniform SGPRs via readlane (zero memory latency)
        float sx[32];
#pragma unroll
        for (int fp = 0; fp < 16; ++fp) {
            const int half = fp >> 3;          // which lane holds these f's
            const int fl = (2 * fp) & 15;      // local f index within the half
            const int j = fl >> 2, c = fl & 3; // xb quad / component (c in {0,2})
            sx[2 * fp] = __uint_as_float(__builtin_amdgcn_readlane(
                __float_as_uint(xb[j][c]), lbase + half));
            sx[2 * fp + 1] = __uint_as_float(__builtin_amdgcn_readlane(
                __float_as_uint(xb[j][c + 1]), lbase + half));
        }

        // 4 independent product chains (ILP); x uniform -> 1-SGPR-rule-clean pk
        f32x2 ta[4], tb[4];
#pragma unroll
        for (int q = 0; q < 4; ++q) {
            f32x2 xp = {sx[2 * q], sx[2 * q + 1]};
            ta[q] = xp * k1a[q] + k0a[q];
            tb[q] = xp * k1b[q] + k0b[q];
        }
#pragma unroll
        for (int fp = 4; fp < 16; ++fp) {
            const int q = fp & 3;
            f32x2 xp = {sx[2 * fp], sx[2 * fp + 1]};
            ta[q] *= xp * k1a[fp] + k0a[fp];
            tb[q] *= xp * k1b[fp] + k0b[fp];
        }
        ta[0] *= ta[1]; ta[2] *= ta[3]; ta[0] *= ta[2];
        tb[0] *= tb[1]; tb[2] *= tb[3]; tb[0] *= tb[2];

        float P = __builtin_fmaf(tb[0][0], tb[0][1], ta[0][0] * ta[0][1]);

        // rank-sum across slots (lane bits 3,4,5)
        P += __shfl_xor(P, 8);
        P += __shfl_xor(P, 16);
        P += __shfl_xor(P, 32);

        const float srsq = __uint_as_float(
            __builtin_amdgcn_readlane(__float_as_uint(rsqv), lbase));
        if (s == 0)
            out[(row0 + i) * UNITS + u] = P * srsq;
    }
}

extern "C" void kernel_launch(void* const* d_in, const int* in_sizes, int n_in,
                              void* d_out, int out_size, void* d_ws, size_t ws_size,
                              hipStream_t stream) {
    const float* X = (const float*)d_in[0];
    const float* K = (const float*)d_in[1];
    float* out = (float*)d_out;
    const int B = in_sizes[0] / F;   // 131072

    dim3 block(64, WPB);                 // 256 threads
    dim3 grid(B / (RPW * WPB));          // 1024 blocks
    hipLaunchKernelGGL(cp_based_kernel, grid, block, 0, stream, X, K, out, B);
}